// Round 4
// baseline (3778.320 us; speedup 1.0000x reference)
//
#include <hip/hip_runtime.h>
#include <math.h>

// Problem constants
#define V_  1024
#define C_  768
#define H_  12
#define L_  8
#define B_  8
#define T_  1024
#define M_  (B_ * T_)      // 8192
#define C3_ (3 * C_)       // 2304
#define C4_ (4 * C_)       // 3072

typedef __bf16 bf16;
typedef __bf16 bf16x8 __attribute__((ext_vector_type(8)));
typedef float  f32x4  __attribute__((ext_vector_type(4)));

// async global->LDS, 16B per lane; LDS dest = wave-uniform base + lane*16
#define GLDS16(g, l) __builtin_amdgcn_global_load_lds(                       \
    (const __attribute__((address_space(1))) void*)(g),                      \
    (__attribute__((address_space(3))) void*)(l), 16, 0, 0)

__device__ __forceinline__ unsigned short bfb(float f) {
    bf16 h = (bf16)f;
    return __builtin_bit_cast(unsigned short, h);
}

// ---------------------------------------------------------------------------
// Embedding (f32)
// ---------------------------------------------------------------------------
__global__ __launch_bounds__(256) void embed_kernel(
    const int* __restrict__ idx, const int* __restrict__ y,
    const float* __restrict__ tok, const float* __restrict__ pos,
    const float* __restrict__ cls, float* __restrict__ x) {
    int row = blockIdx.x;
    int b = row >> 10, t = row & (T_ - 1);
    int tid = threadIdx.x;
    const float* tr = tok + (size_t)idx[row] * C_;
    const float* pr = pos + (size_t)t * C_;
    const float* cr = cls + (size_t)y[b] * C_;
    float* xr = x + (size_t)row * C_;
    for (int c = tid; c < C_; c += 256)
        xr[c] = tr[c] + pr[c] + cr[c];
}

__device__ __forceinline__ float block_sum256(float v, float* red) {
#pragma unroll
    for (int off = 32; off > 0; off >>= 1) v += __shfl_down(v, off);
    __syncthreads();
    if ((threadIdx.x & 63) == 0) red[threadIdx.x >> 6] = v;
    __syncthreads();
    return red[0] + red[1] + red[2] + red[3];
}

// ---------------------------------------------------------------------------
// LayerNorm: f32 in -> bf16 out
// ---------------------------------------------------------------------------
__global__ __launch_bounds__(256) void ln_kernel(
    const float* __restrict__ in, const float* __restrict__ w,
    const float* __restrict__ b, bf16* __restrict__ out) {
    __shared__ float red[4];
    int row = blockIdx.x, tid = threadIdx.x;
    const float* xr = in + (size_t)row * C_;
    float v0 = xr[tid], v1 = xr[tid + 256], v2 = xr[tid + 512];
    float s = block_sum256(v0 + v1 + v2, red);
    float m = s * (1.0f / C_);
    float d0 = v0 - m, d1 = v1 - m, d2 = v2 - m;
    float s2 = block_sum256(d0 * d0 + d1 * d1 + d2 * d2, red);
    float rs = rsqrtf(s2 * (1.0f / C_) + 1e-5f);
    bf16* orow = out + (size_t)row * C_;
    orow[tid]       = (bf16)(d0 * rs * w[tid]       + b[tid]);
    orow[tid + 256] = (bf16)(d1 * rs * w[tid + 256] + b[tid + 256]);
    orow[tid + 512] = (bf16)(d2 * rs * w[tid + 512] + b[tid + 512]);
}

// ---------------------------------------------------------------------------
// Weight transpose + cast: W[K,N] f32 (layer blockIdx.z) -> Wt[N,K] bf16
// ---------------------------------------------------------------------------
__global__ __launch_bounds__(256) void wt_kernel(
    const float* __restrict__ W, bf16* __restrict__ Wt, int K, int N) {
    __shared__ float ts[32][33];
    const size_t sz = (size_t)K * N;
    const float* Ws = W + blockIdx.z * sz;
    bf16* Wts = Wt + blockIdx.z * sz;
    int n0 = blockIdx.x * 32, k0 = blockIdx.y * 32;
    int tx = threadIdx.x & 31, ty = threadIdx.x >> 5;
#pragma unroll
    for (int i = 0; i < 4; ++i)
        ts[ty + i * 8][tx] = Ws[(size_t)(k0 + ty + i * 8) * N + n0 + tx];
    __syncthreads();
#pragma unroll
    for (int i = 0; i < 4; ++i)
        Wts[(size_t)(n0 + ty + i * 8) * K + k0 + tx] = (bf16)ts[tx][ty + i * 8];
}

// ---------------------------------------------------------------------------
// MFMA GEMM: out[M,N] = epi(A[M,K]bf16 @ Bt[N,K]^T + bias) (+res f32)
// 256x128 tile, BK=64, 8 waves (4Mx2N), 512 threads.
// VSPLIT: cols >= 2C go transposed to vt.
// ---------------------------------------------------------------------------
template <int ACT, int BIASF, int RESF, int OBF, int VSPLIT>
__global__ __launch_bounds__(512) void mfma_gemm(
    const bf16* __restrict__ A, const bf16* __restrict__ Bt,
    const float* __restrict__ bias, const float* __restrict__ res,
    void* __restrict__ outp, bf16* __restrict__ vt, int K, int N) {
    __shared__ bf16 As[256 * 64];   // 32 KB
    __shared__ bf16 Bs[128 * 64];   // 16 KB
    const int tid = threadIdx.x;
    const int lane = tid & 63, wave = tid >> 6;
    const int wr = (wave >> 1) * 64, wc = (wave & 1) * 64;
    const int brow = blockIdx.y * 256, bcol = blockIdx.x * 128;
    const int l15 = lane & 15, l4 = lane >> 4;

    const bf16* Ab = A + (size_t)brow * K;
    const bf16* Bb = Bt + (size_t)bcol * K;

    f32x4 acc[4][4];
#pragma unroll
    for (int m = 0; m < 4; ++m)
#pragma unroll
        for (int n = 0; n < 4; ++n)
            acc[m][n] = (f32x4){0.f, 0.f, 0.f, 0.f};

    for (int kt = 0; kt < K; kt += 64) {
        __syncthreads();
#pragma unroll
        for (int i = 0; i < 4; ++i) {
            int j = i * 512 + tid;   // 2048 chunks of 16B = 256x64 bf16
            GLDS16(Ab + (size_t)(j >> 3) * K + kt + (j & 7) * 8, As + j * 8);
        }
#pragma unroll
        for (int i = 0; i < 2; ++i) {
            int j = i * 512 + tid;   // 1024 chunks = 128x64 bf16
            GLDS16(Bb + (size_t)(j >> 3) * K + kt + (j & 7) * 8, Bs + j * 8);
        }
        __syncthreads();
#pragma unroll
        for (int kk = 0; kk < 2; ++kk) {
            bf16x8 af[4], bfr[4];
#pragma unroll
            for (int m = 0; m < 4; ++m)
                af[m] = *(const bf16x8*)(As + (wr + m * 16 + l15) * 64 + kk * 32 + l4 * 8);
#pragma unroll
            for (int n = 0; n < 4; ++n)
                bfr[n] = *(const bf16x8*)(Bs + (wc + n * 16 + l15) * 64 + kk * 32 + l4 * 8);
#pragma unroll
            for (int m = 0; m < 4; ++m)
#pragma unroll
                for (int n = 0; n < 4; ++n)
                    acc[m][n] = __builtin_amdgcn_mfma_f32_16x16x32_bf16(
                        af[m], bfr[n], acc[m][n], 0, 0, 0);
        }
    }

    // epilogue: C/D layout col=lane&15, row=(lane>>4)*4+reg
    if (VSPLIT && bcol >= 2 * C_) {
#pragma unroll
        for (int n = 0; n < 4; ++n) {
            const int col = bcol + wc + n * 16 + l15;
            const float bv = BIASF ? bias[col] : 0.f;
            const int hh = (col - 2 * C_) >> 6;
            const int dd = (col - 2 * C_) & 63;
#pragma unroll
            for (int m = 0; m < 4; ++m) {
                const int row0 = brow + wr + m * 16 + l4 * 4;
                const int bq = row0 >> 10, t0 = row0 & (T_ - 1);
                ushort4 pk;
                pk.x = bfb(acc[m][n][0] + bv);
                pk.y = bfb(acc[m][n][1] + bv);
                pk.z = bfb(acc[m][n][2] + bv);
                pk.w = bfb(acc[m][n][3] + bv);
                *(ushort4*)&vt[(((size_t)bq * H_ + hh) * 64 + dd) * T_ + t0] = pk;
            }
        }
        return;
    }
#pragma unroll
    for (int n = 0; n < 4; ++n) {
        const int col = bcol + wc + n * 16 + l15;
        const float bv = BIASF ? bias[col] : 0.f;
#pragma unroll
        for (int m = 0; m < 4; ++m) {
#pragma unroll
            for (int j = 0; j < 4; ++j) {
                const int row = brow + wr + m * 16 + l4 * 4 + j;
                float v = acc[m][n][j] + bv;
                if (ACT == 1) v = 0.5f * v * (1.f + erff(v * 0.70710678118654752440f));
                if (RESF) v += res[(size_t)row * N + col];
                if (OBF)  ((bf16*)outp)[(size_t)row * N + col] = (bf16)v;
                else      ((float*)outp)[(size_t)row * N + col] = v;
            }
        }
    }
}

// ---------------------------------------------------------------------------
// MFMA flash attention, pipelined. One block per (b, h, 64 q-rows),
// 4 waves x 16 q-rows. K/V double-buffered in LDS; Q in registers.
// Step kt: __syncthreads (drains own prefetch of cur tile), issue prefetch
// of kt+1 into other buffer, compute cur. One barrier per k-tile.
// Swizzle (both sides, rule #21): src col-block bb^(r&7); read cb^((row&7)<<4).
// ---------------------------------------------------------------------------
#define SCL2E 0.18033688011112042592f   // 0.125 * log2(e)

#define ATTN_STAGE(KN, VN, KT)                                               \
    {                                                                        \
        _Pragma("unroll")                                                    \
        for (int i = 0; i < 2; ++i) {                                        \
            int j = i * 256 + tid;                                           \
            int r = j >> 3, bb = j & 7;                                      \
            GLDS16(Kg + (size_t)((KT) * 64 + r) * C3_ + ((bb ^ (r & 7)) << 3), \
                   KN + j * 8);                                              \
            GLDS16(Vg + (size_t)r * T_ + (KT) * 64 + ((bb ^ (r & 7)) << 3),  \
                   VN + j * 8);                                              \
        }                                                                    \
    }

#define ATTN_STEP(KC, VC, KN, VN, KT, PRE)                                   \
    {                                                                        \
        __syncthreads();                                                     \
        if (PRE) ATTN_STAGE(KN, VN, (KT) + 1);                               \
        __builtin_amdgcn_sched_barrier(0);                                   \
        f32x4 acc_s[4];                                                      \
        _Pragma("unroll")                                                    \
        for (int n = 0; n < 4; ++n) acc_s[n] = (f32x4){0.f, 0.f, 0.f, 0.f};  \
        __builtin_amdgcn_s_setprio(1);                                       \
        _Pragma("unroll")                                                    \
        for (int kk = 0; kk < 2; ++kk) {                                     \
            const int cb = kk * 64 + g * 16;                                 \
            bf16x8 aq = kk ? aq1 : aq0;                                      \
            _Pragma("unroll")                                                \
            for (int n = 0; n < 4; ++n) {                                    \
                const int krow = n * 16 + l15;                               \
                bf16x8 bk = *(const bf16x8*)((const char*)KC + krow * 128 +  \
                                             (cb ^ ((krow & 7) << 4)));      \
                acc_s[n] = __builtin_amdgcn_mfma_f32_16x16x32_bf16(          \
                    aq, bk, acc_s[n], 0, 0, 0);                              \
            }                                                                \
        }                                                                    \
        __builtin_amdgcn_s_setprio(0);                                       \
        const bool diag = ((KT) == qt);                                      \
        _Pragma("unroll")                                                    \
        for (int j = 0; j < 4; ++j) {                                        \
            const int qloc = w * 16 + g * 4 + j;                             \
            float sv[4];                                                     \
            _Pragma("unroll")                                                \
            for (int n = 0; n < 4; ++n) {                                    \
                sv[n] = acc_s[n][j];                                         \
                if (diag && (n * 16 + l15 > qloc)) sv[n] = -1e30f;           \
            }                                                                \
            float rm = fmaxf(fmaxf(sv[0], sv[1]), fmaxf(sv[2], sv[3]));      \
            rm = fmaxf(rm, __shfl_xor(rm, 1));                               \
            rm = fmaxf(rm, __shfl_xor(rm, 2));                               \
            rm = fmaxf(rm, __shfl_xor(rm, 4));                               \
            rm = fmaxf(rm, __shfl_xor(rm, 8));                               \
            float mnew = fmaxf(mrun[j], rm);                                 \
            float fs = exp2f((mrun[j] - mnew) * SCL2E);                      \
            mrun[j] = mnew;                                                  \
            float ps = 0.f;                                                  \
            float pv[4];                                                     \
            _Pragma("unroll")                                                \
            for (int n = 0; n < 4; ++n) {                                    \
                pv[n] = exp2f((sv[n] - mnew) * SCL2E);                       \
                ps += pv[n];                                                 \
            }                                                                \
            ps += __shfl_xor(ps, 1);                                         \
            ps += __shfl_xor(ps, 2);                                         \
            ps += __shfl_xor(ps, 4);                                         \
            ps += __shfl_xor(ps, 8);                                         \
            lsum[j] = lsum[j] * fs + ps;                                     \
            _Pragma("unroll")                                                \
            for (int n = 0; n < 4; ++n) acc_o[n][j] *= fs;                   \
            const int row = g * 4 + j;                                       \
            _Pragma("unroll")                                                \
            for (int n = 0; n < 4; ++n) {                                    \
                float po = __shfl_xor(pv[n], 1);                             \
                float lo = (l15 & 1) ? po : pv[n];                           \
                float hi = (l15 & 1) ? pv[n] : po;                           \
                unsigned int u = ((unsigned int)bfb(hi) << 16) | bfb(lo);    \
                if ((n >> 1) == (l15 & 1)) {                                 \
                    int cb = n * 32 + ((l15 & 14) << 1);                     \
                    *(unsigned int*)((char*)Ps[w] + row * 128 +              \
                                     (cb ^ ((row & 7) << 4))) = u;           \
                }                                                            \
            }                                                                \
        }                                                                    \
        __threadfence_block();                                               \
        __builtin_amdgcn_s_setprio(1);                                       \
        _Pragma("unroll")                                                    \
        for (int kk = 0; kk < 2; ++kk) {                                     \
            const int cb = kk * 64 + g * 16;                                 \
            bf16x8 ap = *(const bf16x8*)((const char*)Ps[w] + l15 * 128 +    \
                                         (cb ^ ((l15 & 7) << 4)));           \
            _Pragma("unroll")                                                \
            for (int n = 0; n < 4; ++n) {                                    \
                const int drow = n * 16 + l15;                               \
                bf16x8 bv = *(const bf16x8*)((const char*)VC + drow * 128 +  \
                                             (cb ^ ((drow & 7) << 4)));      \
                acc_o[n] = __builtin_amdgcn_mfma_f32_16x16x32_bf16(          \
                    ap, bv, acc_o[n], 0, 0, 0);                              \
            }                                                                \
        }                                                                    \
        __builtin_amdgcn_s_setprio(0);                                       \
    }

__global__ __launch_bounds__(256) void attn_kernel(
    const bf16* __restrict__ qkv, const bf16* __restrict__ vtb,
    bf16* __restrict__ o) {
    __shared__ bf16 Ks0[64 * 64];
    __shared__ bf16 Ks1[64 * 64];
    __shared__ bf16 Vt0[64 * 64];
    __shared__ bf16 Vt1[64 * 64];
    __shared__ bf16 Ps[4][16 * 64];

    const int qt = gridDim.x - 1 - blockIdx.x;   // heavy tiles first
    const int bh = blockIdx.y;
    const int b = bh / H_, h = bh % H_;
    const int tid = threadIdx.x;
    const int w = tid >> 6, lane = tid & 63;
    const int l15 = lane & 15, g = lane >> 4;

    const bf16* Qg = qkv + ((size_t)(b * T_) + qt * 64) * C3_ + h * 64;
    const bf16* Kg = qkv + (size_t)(b * T_) * C3_ + C_ + h * 64;
    const bf16* Vg = vtb + (size_t)bh * 64 * T_;

    // Q fragments in registers: row = w*16+l15, d = kk*32 + g*8
    bf16x8 aq0 = *(const bf16x8*)(Qg + (size_t)(w * 16 + l15) * C3_ + g * 8);
    bf16x8 aq1 = *(const bf16x8*)(Qg + (size_t)(w * 16 + l15) * C3_ + 32 + g * 8);

    ATTN_STAGE(Ks0, Vt0, 0);   // prologue: stage tile 0

    f32x4 acc_o[4];
#pragma unroll
    for (int n = 0; n < 4; ++n) acc_o[n] = (f32x4){0.f, 0.f, 0.f, 0.f};
    float mrun[4], lsum[4];
#pragma unroll
    for (int j = 0; j < 4; ++j) { mrun[j] = -1e30f; lsum[j] = 0.f; }

    for (int kt = 0; kt <= qt; kt += 2) {
        ATTN_STEP(Ks0, Vt0, Ks1, Vt1, kt, kt < qt);
        if (kt + 1 <= qt)
            ATTN_STEP(Ks1, Vt1, Ks0, Vt0, kt + 1, kt + 1 < qt);
    }

    // ---- write O ----
#pragma unroll
    for (int j = 0; j < 4; ++j) {
        const float inv = 1.f / lsum[j];
        const int orow = qt * 64 + w * 16 + g * 4 + j;
        bf16* op = o + ((size_t)(b * T_) + orow) * C_ + h * 64;
#pragma unroll
        for (int n = 0; n < 4; ++n)
            op[n * 16 + l15] = (bf16)(acc_o[n][j] * inv);
    }
}

// ---------------------------------------------------------------------------
// Launch
// ---------------------------------------------------------------------------
extern "C" void kernel_launch(void* const* d_in, const int* in_sizes, int n_in,
                              void* d_out, int out_size, void* d_ws, size_t ws_size,
                              hipStream_t stream) {
    (void)in_sizes; (void)n_in; (void)out_size; (void)ws_size;
    const int*   idx  = (const int*)d_in[0];
    const int*   y    = (const int*)d_in[1];
    const float* tok  = (const float*)d_in[2];
    const float* pos  = (const float*)d_in[3];
    const float* cls  = (const float*)d_in[4];
    const float* ln1w = (const float*)d_in[5];
    const float* ln1b = (const float*)d_in[6];
    const float* aw   = (const float*)d_in[7];
    const float* ab   = (const float*)d_in[8];
    const float* pw   = (const float*)d_in[9];
    const float* pb   = (const float*)d_in[10];
    const float* ln2w = (const float*)d_in[11];
    const float* ln2b = (const float*)d_in[12];
    const float* w1   = (const float*)d_in[13];
    const float* b1   = (const float*)d_in[14];
    const float* w2   = (const float*)d_in[15];
    const float* b2   = (const float*)d_in[16];
    const float* lnfw = (const float*)d_in[17];
    const float* lnfb = (const float*)d_in[18];
    const float* hw   = (const float*)d_in[19];
    float* out = (float*)d_out;

    // Workspace: x(f32) | union{qkv bf16 + vt bf16 | mid bf16} | hbf | weights
    char* wsp = (char*)d_ws;
    float* x   = (float*)wsp;  wsp += (size_t)M_ * C_ * 4;
    char*  uni = wsp;          wsp += (size_t)M_ * C4_ * 2;
    bf16*  qkv = (bf16*)uni;                                   // M x 3C
    bf16*  vtb = (bf16*)(uni + (size_t)M_ * C3_ * 2);          // B*H*64 x T
    bf16*  mid = (bf16*)uni;                                   // M x 4C
    bf16*  hbf = (bf16*)wsp;   wsp += (size_t)M_ * C_ * 2;
    bf16*  awt = (bf16*)wsp;   wsp += (size_t)L_ * C_ * C3_ * 2;
    bf16*  pwt = (bf16*)wsp;   wsp += (size_t)L_ * C_ * C_  * 2;
    bf16*  w1t = (bf16*)wsp;   wsp += (size_t)L_ * C_ * C4_ * 2;
    bf16*  w2t = (bf16*)wsp;   wsp += (size_t)L_ * C4_ * C_ * 2;
    bf16*  hwt = (bf16*)wsp;   wsp += (size_t)C_ * V_ * 2;

    wt_kernel<<<dim3(C3_ / 32, C_ / 32, L_), 256, 0, stream>>>(aw, awt, C_, C3_);
    wt_kernel<<<dim3(C_ / 32, C_ / 32, L_), 256, 0, stream>>>(pw, pwt, C_, C_);
    wt_kernel<<<dim3(C4_ / 32, C_ / 32, L_), 256, 0, stream>>>(w1, w1t, C_, C4_);
    wt_kernel<<<dim3(C_ / 32, C4_ / 32, L_), 256, 0, stream>>>(w2, w2t, C4_, C_);
    wt_kernel<<<dim3(V_ / 32, C_ / 32, 1), 256, 0, stream>>>(hw, hwt, C_, V_);

    embed_kernel<<<M_, 256, 0, stream>>>(idx, y, tok, pos, cls, x);

    for (int l = 0; l < L_; ++l) {
        ln_kernel<<<M_, 256, 0, stream>>>(x, ln1w + l * C_, ln1b + l * C_, hbf);

        mfma_gemm<0, 1, 0, 1, 1><<<dim3(C3_ / 128, M_ / 256), 512, 0, stream>>>(
            hbf, awt + (size_t)l * C_ * C3_, ab + (size_t)l * C3_, nullptr,
            qkv, vtb, C_, C3_);

        attn_kernel<<<dim3(T_ / 64, B_ * H_), 256, 0, stream>>>(qkv, vtb, hbf);

        mfma_gemm<0, 1, 1, 0, 0><<<dim3(C_ / 128, M_ / 256), 512, 0, stream>>>(
            hbf, pwt + (size_t)l * C_ * C_, pb + (size_t)l * C_, x,
            x, nullptr, C_, C_);

        ln_kernel<<<M_, 256, 0, stream>>>(x, ln2w + l * C_, ln2b + l * C_, hbf);

        mfma_gemm<1, 1, 0, 1, 0><<<dim3(C4_ / 128, M_ / 256), 512, 0, stream>>>(
            hbf, w1t + (size_t)l * C_ * C4_, b1 + (size_t)l * C4_, nullptr,
            mid, nullptr, C_, C4_);

        mfma_gemm<0, 1, 1, 0, 0><<<dim3(C_ / 128, M_ / 256), 512, 0, stream>>>(
            mid, w2t + (size_t)l * C4_ * C_, b2 + (size_t)l * C_, x,
            x, nullptr, C4_, C_);
    }

    ln_kernel<<<M_, 256, 0, stream>>>(x, lnfw, lnfb, hbf);

    mfma_gemm<0, 0, 0, 0, 0><<<dim3(V_ / 128, M_ / 256), 512, 0, stream>>>(
        hbf, hwt, nullptr, nullptr, out, nullptr, C_, V_);
}

// Round 5
// 2917.414 us; speedup vs baseline: 1.2951x; 1.2951x over previous
//
#include <hip/hip_runtime.h>
#include <math.h>

// Problem constants
#define V_  1024
#define C_  768
#define H_  12
#define L_  8
#define B_  8
#define T_  1024
#define M_  (B_ * T_)      // 8192
#define C3_ (3 * C_)       // 2304
#define C4_ (4 * C_)       // 3072

#define SCL2E 0.18033688011112042592f   // 0.125 * log2(e), folded into Q

typedef __bf16 bf16;
typedef __bf16 bf16x8 __attribute__((ext_vector_type(8)));
typedef float  f32x4  __attribute__((ext_vector_type(4)));
typedef unsigned int u32x4 __attribute__((ext_vector_type(4)));

// async global->LDS, 16B per lane; LDS dest = wave-uniform base + lane*16
#define GLDS16(g, l) __builtin_amdgcn_global_load_lds(                       \
    (const __attribute__((address_space(1))) void*)(g),                      \
    (__attribute__((address_space(3))) void*)(l), 16, 0, 0)

__device__ __forceinline__ unsigned short bfb(float f) {
    bf16 h = (bf16)f;
    return __builtin_bit_cast(unsigned short, h);
}

// ---------------------------------------------------------------------------
// Embedding (f32)
// ---------------------------------------------------------------------------
__global__ __launch_bounds__(256) void embed_kernel(
    const int* __restrict__ idx, const int* __restrict__ y,
    const float* __restrict__ tok, const float* __restrict__ pos,
    const float* __restrict__ cls, float* __restrict__ x) {
    int row = blockIdx.x;
    int b = row >> 10, t = row & (T_ - 1);
    int tid = threadIdx.x;
    const float* tr = tok + (size_t)idx[row] * C_;
    const float* pr = pos + (size_t)t * C_;
    const float* cr = cls + (size_t)y[b] * C_;
    float* xr = x + (size_t)row * C_;
    for (int c = tid; c < C_; c += 256)
        xr[c] = tr[c] + pr[c] + cr[c];
}

__device__ __forceinline__ float block_sum256(float v, float* red) {
#pragma unroll
    for (int off = 32; off > 0; off >>= 1) v += __shfl_down(v, off);
    __syncthreads();
    if ((threadIdx.x & 63) == 0) red[threadIdx.x >> 6] = v;
    __syncthreads();
    return red[0] + red[1] + red[2] + red[3];
}

// ---------------------------------------------------------------------------
// LayerNorm: f32 in -> bf16 out
// ---------------------------------------------------------------------------
__global__ __launch_bounds__(256) void ln_kernel(
    const float* __restrict__ in, const float* __restrict__ w,
    const float* __restrict__ b, bf16* __restrict__ out) {
    __shared__ float red[4];
    int row = blockIdx.x, tid = threadIdx.x;
    const float* xr = in + (size_t)row * C_;
    float v0 = xr[tid], v1 = xr[tid + 256], v2 = xr[tid + 512];
    float s = block_sum256(v0 + v1 + v2, red);
    float m = s * (1.0f / C_);
    float d0 = v0 - m, d1 = v1 - m, d2 = v2 - m;
    float s2 = block_sum256(d0 * d0 + d1 * d1 + d2 * d2, red);
    float rs = rsqrtf(s2 * (1.0f / C_) + 1e-5f);
    bf16* orow = out + (size_t)row * C_;
    orow[tid]       = (bf16)(d0 * rs * w[tid]       + b[tid]);
    orow[tid + 256] = (bf16)(d1 * rs * w[tid + 256] + b[tid + 256]);
    orow[tid + 512] = (bf16)(d2 * rs * w[tid + 512] + b[tid + 512]);
}

// ---------------------------------------------------------------------------
// Weight transpose + cast: W[K,N] f32 (layer blockIdx.z) -> Wt[N,K] bf16
// ---------------------------------------------------------------------------
__global__ __launch_bounds__(256) void wt_kernel(
    const float* __restrict__ W, bf16* __restrict__ Wt, int K, int N) {
    __shared__ float ts[32][33];
    const size_t sz = (size_t)K * N;
    const float* Ws = W + blockIdx.z * sz;
    bf16* Wts = Wt + blockIdx.z * sz;
    int n0 = blockIdx.x * 32, k0 = blockIdx.y * 32;
    int tx = threadIdx.x & 31, ty = threadIdx.x >> 5;
#pragma unroll
    for (int i = 0; i < 4; ++i)
        ts[ty + i * 8][tx] = Ws[(size_t)(k0 + ty + i * 8) * N + n0 + tx];
    __syncthreads();
#pragma unroll
    for (int i = 0; i < 4; ++i)
        Wts[(size_t)(n0 + ty + i * 8) * K + k0 + tx] = (bf16)ts[tx][ty + i * 8];
}

// ---------------------------------------------------------------------------
// MFMA GEMM: out[M,N] = epi(A[M,K]bf16 @ Bt[N,K]^T + bias) (+res f32)
// 128x128 tile, BK=64, 4 waves (r3-proven config).
// VSPLIT: cols >= 2C go transposed to vt; cols < C (Q) pre-scaled by SCL2E.
// ---------------------------------------------------------------------------
template <int ACT, int BIASF, int RESF, int OBF, int VSPLIT>
__global__ __launch_bounds__(256) void mfma_gemm(
    const bf16* __restrict__ A, const bf16* __restrict__ Bt,
    const float* __restrict__ bias, const float* __restrict__ res,
    void* __restrict__ outp, bf16* __restrict__ vt, int K, int N) {
    __shared__ bf16 As[128 * 64];
    __shared__ bf16 Bs[128 * 64];
    const int tid = threadIdx.x;
    const int lane = tid & 63, wave = tid >> 6;
    const int wr = (wave >> 1) * 64, wc = (wave & 1) * 64;
    const int brow = blockIdx.y * 128, bcol = blockIdx.x * 128;
    const int l15 = lane & 15, l4 = lane >> 4;

    const bf16* Ab = A + (size_t)brow * K;
    const bf16* Bb = Bt + (size_t)bcol * K;

    f32x4 acc[4][4];
#pragma unroll
    for (int m = 0; m < 4; ++m)
#pragma unroll
        for (int n = 0; n < 4; ++n)
            acc[m][n] = (f32x4){0.f, 0.f, 0.f, 0.f};

    for (int kt = 0; kt < K; kt += 64) {
        __syncthreads();
#pragma unroll
        for (int i = 0; i < 4; ++i) {
            int j = i * 256 + tid;
            GLDS16(Ab + (size_t)(j >> 3) * K + kt + (j & 7) * 8, As + j * 8);
        }
#pragma unroll
        for (int i = 0; i < 4; ++i) {
            int j = i * 256 + tid;
            GLDS16(Bb + (size_t)(j >> 3) * K + kt + (j & 7) * 8, Bs + j * 8);
        }
        __syncthreads();
#pragma unroll
        for (int kk = 0; kk < 2; ++kk) {
            bf16x8 af[4], bfr[4];
#pragma unroll
            for (int m = 0; m < 4; ++m)
                af[m] = *(const bf16x8*)(As + (wr + m * 16 + l15) * 64 + kk * 32 + l4 * 8);
#pragma unroll
            for (int n = 0; n < 4; ++n)
                bfr[n] = *(const bf16x8*)(Bs + (wc + n * 16 + l15) * 64 + kk * 32 + l4 * 8);
#pragma unroll
            for (int m = 0; m < 4; ++m)
#pragma unroll
                for (int n = 0; n < 4; ++n)
                    acc[m][n] = __builtin_amdgcn_mfma_f32_16x16x32_bf16(
                        af[m], bfr[n], acc[m][n], 0, 0, 0);
        }
    }

    // epilogue: C/D layout col=lane&15, row=(lane>>4)*4+reg
    if (VSPLIT && bcol >= 2 * C_) {
        // V third of qkv: write transposed to vt[(b*H+h)*64+d][t] (bf16)
#pragma unroll
        for (int n = 0; n < 4; ++n) {
            const int col = bcol + wc + n * 16 + l15;
            const float bv = BIASF ? bias[col] : 0.f;
            const int hh = (col - 2 * C_) >> 6;
            const int dd = (col - 2 * C_) & 63;
#pragma unroll
            for (int m = 0; m < 4; ++m) {
                const int row0 = brow + wr + m * 16 + l4 * 4;
                const int bq = row0 >> 10, t0 = row0 & (T_ - 1);
                ushort4 pk;
                pk.x = bfb(acc[m][n][0] + bv);
                pk.y = bfb(acc[m][n][1] + bv);
                pk.z = bfb(acc[m][n][2] + bv);
                pk.w = bfb(acc[m][n][3] + bv);
                *(ushort4*)&vt[(((size_t)bq * H_ + hh) * 64 + dd) * T_ + t0] = pk;
            }
        }
        return;
    }
#pragma unroll
    for (int n = 0; n < 4; ++n) {
        const int col = bcol + wc + n * 16 + l15;
        const float bv = BIASF ? bias[col] : 0.f;
#pragma unroll
        for (int m = 0; m < 4; ++m) {
#pragma unroll
            for (int j = 0; j < 4; ++j) {
                const int row = brow + wr + m * 16 + l4 * 4 + j;
                float v = acc[m][n][j] + bv;
                if (ACT == 1) v = 0.5f * v * (1.f + erff(v * 0.70710678118654752440f));
                if (VSPLIT && col < C_) v *= SCL2E;   // pre-scale Q for attn
                if (RESF) v += res[(size_t)row * N + col];
                if (OBF)  ((bf16*)outp)[(size_t)row * N + col] = (bf16)v;
                else      ((float*)outp)[(size_t)row * N + col] = v;
            }
        }
    }
}

// ---------------------------------------------------------------------------
// MFMA flash attention, swapped operands (lane-local softmax).
// One block per (b, h, 128 q-rows); 8 waves x 16 q-rows; KVBLK=64, dbuf LDS.
// QK^T: mfma(K,Q) -> S[k][q]: lane owns q = lane&15, 16 k's in-lane
//   (k = n*16 + g*4 + j, g = lane>>4). Row max/sum: in-lane tree + xor16/32.
// P pack: j-adjacent k pairs are in-lane -> bf16x2 words, no LDS round-trip.
// PV: mfma(V^T, P^T) -> O^T[d][q]: col = lane&15 = q  => fs/inv rescale
//   in-lane, zero broadcasts. P^T B-frag built by 16 independent shuffles.
// ---------------------------------------------------------------------------
__device__ __forceinline__ void attn_stage(
    bf16* KN, bf16* VN, int kt,
    const bf16* __restrict__ Kg, const bf16* __restrict__ Vg, int tid) {
    const int r = tid >> 3, bb = tid & 7;
    GLDS16(Kg + (size_t)(kt * 64 + r) * C3_ + ((bb ^ (r & 7)) << 3), KN + tid * 8);
    GLDS16(Vg + (size_t)r * T_ + kt * 64 + ((bb ^ (r & 7)) << 3), VN + tid * 8);
}

__device__ __forceinline__ void attn_step(
    const bf16* KC, const bf16* VC, bf16* KN, bf16* VN,
    const bf16* __restrict__ Kg, const bf16* __restrict__ Vg,
    bf16x8 aq0, bf16x8 aq1, f32x4 (&acc_o)[4], float& mrun, float& lsum,
    int kt, bool pre, bool msk, int qg, int tid, int l15, int g) {
    __syncthreads();                       // prev reads done + own prefetch drained
    if (pre) attn_stage(KN, VN, kt + 1, Kg, Vg, tid);
    __builtin_amdgcn_sched_barrier(0);

    // ---- QK^T (swapped): acc_s[n][j] = S[k = kt*64+n*16+g*4+j][q = qg] ----
    f32x4 acc_s[4];
#pragma unroll
    for (int n = 0; n < 4; ++n) acc_s[n] = (f32x4){0.f, 0.f, 0.f, 0.f};
    __builtin_amdgcn_s_setprio(1);
#pragma unroll
    for (int kk = 0; kk < 2; ++kk) {
        bf16x8 aq = kk ? aq1 : aq0;
        const int cb = kk * 64 + g * 16;
#pragma unroll
        for (int n = 0; n < 4; ++n) {
            const int krow = n * 16 + l15;
            bf16x8 bk = *(const bf16x8*)((const char*)KC + krow * 128 +
                                         (cb ^ ((krow & 7) << 4)));
            acc_s[n] = __builtin_amdgcn_mfma_f32_16x16x32_bf16(
                bk, aq, acc_s[n], 0, 0, 0);
        }
    }
    __builtin_amdgcn_s_setprio(0);

    // ---- lane-local online softmax (q = l15 owned by this lane) ----
    float pv[4][4];
    float rm = -1e30f;
#pragma unroll
    for (int n = 0; n < 4; ++n)
#pragma unroll
        for (int j = 0; j < 4; ++j) {
            float s = acc_s[n][j];
            if (msk && (kt * 64 + n * 16 + g * 4 + j > qg)) s = -1e30f;
            pv[n][j] = s;
            rm = fmaxf(rm, s);
        }
    rm = fmaxf(rm, __shfl_xor(rm, 16));
    rm = fmaxf(rm, __shfl_xor(rm, 32));
    const float mnew = fmaxf(mrun, rm);
    const float fs = exp2f(mrun - mnew);
    mrun = mnew;
    float ps = 0.f;
#pragma unroll
    for (int n = 0; n < 4; ++n)
#pragma unroll
        for (int j = 0; j < 4; ++j) {
            pv[n][j] = exp2f(pv[n][j] - mnew);
            ps += pv[n][j];
        }
    ps += __shfl_xor(ps, 16);
    ps += __shfl_xor(ps, 32);
    lsum = lsum * fs + ps;
#pragma unroll
    for (int n = 0; n < 4; ++n) {
        acc_o[n][0] *= fs; acc_o[n][1] *= fs;
        acc_o[n][2] *= fs; acc_o[n][3] *= fs;
    }

    // ---- pack P to bf16x2 words (in-lane: j-adjacent k) ----
    unsigned int pkw[4][2];
#pragma unroll
    for (int n = 0; n < 4; ++n) {
        pkw[n][0] = ((unsigned int)bfb(pv[n][1]) << 16) | bfb(pv[n][0]);
        pkw[n][1] = ((unsigned int)bfb(pv[n][3]) << 16) | bfb(pv[n][2]);
    }

    // ---- PV (swapped): acc_o[n] += V^T x P^T ; O[d][q=l15] ----
    const int sA = l15 + (((2 * g) & 3) << 4);
    const int sB = l15 + (((2 * g + 1) & 3) << 4);
    __builtin_amdgcn_s_setprio(1);
#pragma unroll
    for (int kk = 0; kk < 2; ++kk) {
        const unsigned int a0 = __shfl((int)pkw[2 * kk + 0][0], sA);
        const unsigned int a1 = __shfl((int)pkw[2 * kk + 0][1], sA);
        const unsigned int a2 = __shfl((int)pkw[2 * kk + 0][0], sB);
        const unsigned int a3 = __shfl((int)pkw[2 * kk + 0][1], sB);
        const unsigned int b0 = __shfl((int)pkw[2 * kk + 1][0], sA);
        const unsigned int b1 = __shfl((int)pkw[2 * kk + 1][1], sA);
        const unsigned int b2 = __shfl((int)pkw[2 * kk + 1][0], sB);
        const unsigned int b3 = __shfl((int)pkw[2 * kk + 1][1], sB);
        u32x4 wd;
        wd[0] = (g & 2) ? b0 : a0;
        wd[1] = (g & 2) ? b1 : a1;
        wd[2] = (g & 2) ? b2 : a2;
        wd[3] = (g & 2) ? b3 : a3;
        bf16x8 ap = __builtin_bit_cast(bf16x8, wd);
        const int cb = kk * 64 + g * 16;
#pragma unroll
        for (int n = 0; n < 4; ++n) {
            const int drow = n * 16 + l15;
            bf16x8 bv = *(const bf16x8*)((const char*)VC + drow * 128 +
                                         (cb ^ ((drow & 7) << 4)));
            acc_o[n] = __builtin_amdgcn_mfma_f32_16x16x32_bf16(
                bv, ap, acc_o[n], 0, 0, 0);
        }
    }
    __builtin_amdgcn_s_setprio(0);
}

__global__ __launch_bounds__(512, 4) void attn_kernel(
    const bf16* __restrict__ qkv, const bf16* __restrict__ vtb,
    bf16* __restrict__ o) {
    __shared__ bf16 Ks0[64 * 64];
    __shared__ bf16 Vt0[64 * 64];
    __shared__ bf16 Ks1[64 * 64];
    __shared__ bf16 Vt1[64 * 64];

    const int qt = 7 - blockIdx.x;          // heavy tiles first
    const int bh = blockIdx.y;
    const int b = bh / H_, h = bh % H_;
    const int tid = threadIdx.x;
    const int w = tid >> 6, lane = tid & 63;
    const int l15 = lane & 15, g = lane >> 4;
    const int qg = qt * 128 + w * 16 + l15; // this lane's q-row (local to bh)

    const bf16* Qg = qkv + ((size_t)(b * T_) + qt * 128) * C3_ + h * 64;
    const bf16* Kg = qkv + (size_t)(b * T_) * C3_ + C_ + h * 64;
    const bf16* Vg = vtb + (size_t)bh * 64 * T_;

    // Q fragments in registers (B-operand: col=l15=q, k=g*8..), pre-scaled
    bf16x8 aq0 = *(const bf16x8*)(Qg + (size_t)(w * 16 + l15) * C3_ + g * 8);
    bf16x8 aq1 = *(const bf16x8*)(Qg + (size_t)(w * 16 + l15) * C3_ + 32 + g * 8);

    attn_stage(Ks0, Vt0, 0, Kg, Vg, tid);   // prologue

    f32x4 acc_o[4];
#pragma unroll
    for (int n = 0; n < 4; ++n) acc_o[n] = (f32x4){0.f, 0.f, 0.f, 0.f};
    float mrun = -1e30f, lsum = 0.f;

    const int ktN = 2 * qt + 1;             // inclusive last k-tile
    const int dmin = 2 * qt + (w >> 2);     // first tile needing mask (per wave)

    for (int kt = 0; kt < ktN; kt += 2) {
        attn_step(Ks0, Vt0, Ks1, Vt1, Kg, Vg, aq0, aq1, acc_o, mrun, lsum,
                  kt, true, kt >= dmin, qg, tid, l15, g);
        attn_step(Ks1, Vt1, Ks0, Vt0, Kg, Vg, aq0, aq1, acc_o, mrun, lsum,
                  kt + 1, kt + 2 <= ktN, kt + 1 >= dmin, qg, tid, l15, g);
    }

    // ---- write O: lane owns q=qg, d = n*16 + g*4 + j ----
    const float inv = 1.f / lsum;
    bf16* op = o + ((size_t)(b * T_) + qg) * C_ + h * 64;
#pragma unroll
    for (int n = 0; n < 4; ++n) {
        ushort4 pk;
        pk.x = bfb(acc_o[n][0] * inv);
        pk.y = bfb(acc_o[n][1] * inv);
        pk.z = bfb(acc_o[n][2] * inv);
        pk.w = bfb(acc_o[n][3] * inv);
        *(ushort4*)&op[n * 16 + g * 4] = pk;
    }
}

// ---------------------------------------------------------------------------
// Launch
// ---------------------------------------------------------------------------
extern "C" void kernel_launch(void* const* d_in, const int* in_sizes, int n_in,
                              void* d_out, int out_size, void* d_ws, size_t ws_size,
                              hipStream_t stream) {
    (void)in_sizes; (void)n_in; (void)out_size; (void)ws_size;
    const int*   idx  = (const int*)d_in[0];
    const int*   y    = (const int*)d_in[1];
    const float* tok  = (const float*)d_in[2];
    const float* pos  = (const float*)d_in[3];
    const float* cls  = (const float*)d_in[4];
    const float* ln1w = (const float*)d_in[5];
    const float* ln1b = (const float*)d_in[6];
    const float* aw   = (const float*)d_in[7];
    const float* ab   = (const float*)d_in[8];
    const float* pw   = (const float*)d_in[9];
    const float* pb   = (const float*)d_in[10];
    const float* ln2w = (const float*)d_in[11];
    const float* ln2b = (const float*)d_in[12];
    const float* w1   = (const float*)d_in[13];
    const float* b1   = (const float*)d_in[14];
    const float* w2   = (const float*)d_in[15];
    const float* b2   = (const float*)d_in[16];
    const float* lnfw = (const float*)d_in[17];
    const float* lnfb = (const float*)d_in[18];
    const float* hw   = (const float*)d_in[19];
    float* out = (float*)d_out;

    // Workspace: x(f32) | union{qkv bf16 + vt bf16 | mid bf16} | hbf | weights
    char* wsp = (char*)d_ws;
    float* x   = (float*)wsp;  wsp += (size_t)M_ * C_ * 4;
    char*  uni = wsp;          wsp += (size_t)M_ * C4_ * 2;
    bf16*  qkv = (bf16*)uni;                                   // M x 3C
    bf16*  vtb = (bf16*)(uni + (size_t)M_ * C3_ * 2);          // B*H*64 x T
    bf16*  mid = (bf16*)uni;                                   // M x 4C
    bf16*  hbf = (bf16*)wsp;   wsp += (size_t)M_ * C_ * 2;
    bf16*  awt = (bf16*)wsp;   wsp += (size_t)L_ * C_ * C3_ * 2;
    bf16*  pwt = (bf16*)wsp;   wsp += (size_t)L_ * C_ * C_  * 2;
    bf16*  w1t = (bf16*)wsp;   wsp += (size_t)L_ * C_ * C4_ * 2;
    bf16*  w2t = (bf16*)wsp;   wsp += (size_t)L_ * C4_ * C_ * 2;
    bf16*  hwt = (bf16*)wsp;   wsp += (size_t)C_ * V_ * 2;

    wt_kernel<<<dim3(C3_ / 32, C_ / 32, L_), 256, 0, stream>>>(aw, awt, C_, C3_);
    wt_kernel<<<dim3(C_ / 32, C_ / 32, L_), 256, 0, stream>>>(pw, pwt, C_, C_);
    wt_kernel<<<dim3(C4_ / 32, C_ / 32, L_), 256, 0, stream>>>(w1, w1t, C_, C4_);
    wt_kernel<<<dim3(C_ / 32, C4_ / 32, L_), 256, 0, stream>>>(w2, w2t, C4_, C_);
    wt_kernel<<<dim3(V_ / 32, C_ / 32, 1), 256, 0, stream>>>(hw, hwt, C_, V_);

    embed_kernel<<<M_, 256, 0, stream>>>(idx, y, tok, pos, cls, x);

    for (int l = 0; l < L_; ++l) {
        ln_kernel<<<M_, 256, 0, stream>>>(x, ln1w + l * C_, ln1b + l * C_, hbf);

        mfma_gemm<0, 1, 0, 1, 1><<<dim3(C3_ / 128, M_ / 128), 256, 0, stream>>>(
            hbf, awt + (size_t)l * C_ * C3_, ab + (size_t)l * C3_, nullptr,
            qkv, vtb, C_, C3_);

        attn_kernel<<<dim3(T_ / 128, B_ * H_), 512, 0, stream>>>(qkv, vtb, hbf);

        mfma_gemm<0, 1, 1, 0, 0><<<dim3(C_ / 128, M_ / 128), 256, 0, stream>>>(
            hbf, pwt + (size_t)l * C_ * C_, pb + (size_t)l * C_, x,
            x, nullptr, C_, C_);

        ln_kernel<<<M_, 256, 0, stream>>>(x, ln2w + l * C_, ln2b + l * C_, hbf);

        mfma_gemm<1, 1, 0, 1, 0><<<dim3(C4_ / 128, M_ / 128), 256, 0, stream>>>(
            hbf, w1t + (size_t)l * C_ * C4_, b1 + (size_t)l * C4_, nullptr,
            mid, nullptr, C_, C4_);

        mfma_gemm<0, 1, 1, 0, 0><<<dim3(C_ / 128, M_ / 128), 256, 0, stream>>>(
            mid, w2t + (size_t)l * C4_ * C_, b2 + (size_t)l * C_, x,
            x, nullptr, C4_, C_);
    }

    ln_kernel<<<M_, 256, 0, stream>>>(x, lnfw, lnfb, hbf);

    mfma_gemm<0, 0, 0, 0, 0><<<dim3(V_ / 128, M_ / 128), 256, 0, stream>>>(
        hbf, hwt, nullptr, nullptr, out, nullptr, C_, V_);
}

// Round 7
// 2608.761 us; speedup vs baseline: 1.4483x; 1.1183x over previous
//
#include <hip/hip_runtime.h>
#include <math.h>

// Problem constants
#define V_  1024
#define C_  768
#define H_  12
#define L_  8
#define B_  8
#define T_  1024
#define M_  (B_ * T_)      // 8192
#define C3_ (3 * C_)       // 2304
#define C4_ (4 * C_)       // 3072

#define SCL2E 0.18033688011112042592f   // 0.125 * log2(e), folded into Q

typedef __bf16 bf16;
typedef __bf16 bf16x8 __attribute__((ext_vector_type(8)));
typedef float  f32x4  __attribute__((ext_vector_type(4)));
typedef unsigned int u32x4 __attribute__((ext_vector_type(4)));

// async global->LDS, 16B per lane; LDS dest = wave-uniform base + lane*16
#define GLDS16(g, l) __builtin_amdgcn_global_load_lds(                       \
    (const __attribute__((address_space(1))) void*)(g),                      \
    (__attribute__((address_space(3))) void*)(l), 16, 0, 0)

__device__ __forceinline__ unsigned short bfb(float f) {
    bf16 h = (bf16)f;
    return __builtin_bit_cast(unsigned short, h);
}

// ---------------------------------------------------------------------------
// Embedding (f32)
// ---------------------------------------------------------------------------
__global__ __launch_bounds__(256) void embed_kernel(
    const int* __restrict__ idx, const int* __restrict__ y,
    const float* __restrict__ tok, const float* __restrict__ pos,
    const float* __restrict__ cls, float* __restrict__ x) {
    int row = blockIdx.x;
    int b = row >> 10, t = row & (T_ - 1);
    int tid = threadIdx.x;
    const float* tr = tok + (size_t)idx[row] * C_;
    const float* pr = pos + (size_t)t * C_;
    const float* cr = cls + (size_t)y[b] * C_;
    float* xr = x + (size_t)row * C_;
    for (int c = tid; c < C_; c += 256)
        xr[c] = tr[c] + pr[c] + cr[c];
}

// ---------------------------------------------------------------------------
// LayerNorm: one WAVE per row (4 rows / 256-thr block), float4 loads,
// pure shfl_xor reduce, no barriers. f32 in -> bf16 out.
// ---------------------------------------------------------------------------
__global__ __launch_bounds__(256) void ln_kernel(
    const float* __restrict__ in, const float* __restrict__ w,
    const float* __restrict__ b, bf16* __restrict__ out) {
    const int row = blockIdx.x * 4 + (threadIdx.x >> 6);
    const int lane = threadIdx.x & 63;
    const int c0 = lane * 4;
    const float* xr = in + (size_t)row * C_;
    float4 v0 = *(const float4*)&xr[c0];
    float4 v1 = *(const float4*)&xr[c0 + 256];
    float4 v2 = *(const float4*)&xr[c0 + 512];
    float s = v0.x + v0.y + v0.z + v0.w + v1.x + v1.y + v1.z + v1.w +
              v2.x + v2.y + v2.z + v2.w;
    float s2 = v0.x * v0.x + v0.y * v0.y + v0.z * v0.z + v0.w * v0.w +
               v1.x * v1.x + v1.y * v1.y + v1.z * v1.z + v1.w * v1.w +
               v2.x * v2.x + v2.y * v2.y + v2.z * v2.z + v2.w * v2.w;
#pragma unroll
    for (int off = 1; off < 64; off <<= 1) {
        s  += __shfl_xor(s, off);
        s2 += __shfl_xor(s2, off);
    }
    const float m = s * (1.0f / C_);
    const float var = s2 * (1.0f / C_) - m * m;
    const float rs = rsqrtf(var + 1e-5f);
    bf16* orow = out + (size_t)row * C_;
#pragma unroll
    for (int p = 0; p < 3; ++p) {
        const int c = c0 + p * 256;
        float4 v = p == 0 ? v0 : (p == 1 ? v1 : v2);
        float4 wv = *(const float4*)&w[c];
        float4 bv = *(const float4*)&b[c];
        ushort4 pk;
        pk.x = bfb((v.x - m) * rs * wv.x + bv.x);
        pk.y = bfb((v.y - m) * rs * wv.y + bv.y);
        pk.z = bfb((v.z - m) * rs * wv.z + bv.z);
        pk.w = bfb((v.w - m) * rs * wv.w + bv.w);
        *(ushort4*)&orow[c] = pk;
    }
}

// ---------------------------------------------------------------------------
// Weight transpose + cast: W[K,N] f32 (layer blockIdx.z) -> Wt[N,K] bf16
// ---------------------------------------------------------------------------
__global__ __launch_bounds__(256) void wt_kernel(
    const float* __restrict__ W, bf16* __restrict__ Wt, int K, int N) {
    __shared__ float ts[32][33];
    const size_t sz = (size_t)K * N;
    const float* Ws = W + blockIdx.z * sz;
    bf16* Wts = Wt + blockIdx.z * sz;
    int n0 = blockIdx.x * 32, k0 = blockIdx.y * 32;
    int tx = threadIdx.x & 31, ty = threadIdx.x >> 5;
#pragma unroll
    for (int i = 0; i < 4; ++i)
        ts[ty + i * 8][tx] = Ws[(size_t)(k0 + ty + i * 8) * N + n0 + tx];
    __syncthreads();
#pragma unroll
    for (int i = 0; i < 4; ++i)
        Wts[(size_t)(n0 + ty + i * 8) * K + k0 + tx] = (bf16)ts[tx][ty + i * 8];
}

// ---------------------------------------------------------------------------
// MFMA GEMM, pipelined dbuf (T3-minimum 2-phase):
// out[M,N] = epi(A[M,K]bf16 @ Bt[N,K]^T + bias) (+res f32)
// 128x128 tile, BK=64 double-buffered; per step: sync -> issue next-tile
// global_load_lds -> sched_barrier -> compute current. One barrier/K-tile.
// VSPLIT: cols >= 2C go transposed to vt; cols < C (Q) pre-scaled by SCL2E.
// ---------------------------------------------------------------------------
#define GSTAGE(AS, BS, KT)                                                   \
    {                                                                        \
        _Pragma("unroll")                                                    \
        for (int i = 0; i < 4; ++i) {                                        \
            int j = i * 256 + tid;                                           \
            GLDS16(Ab + (size_t)(j >> 3) * K + (KT) + (j & 7) * 8, AS + j * 8); \
        }                                                                    \
        _Pragma("unroll")                                                    \
        for (int i = 0; i < 4; ++i) {                                        \
            int j = i * 256 + tid;                                           \
            GLDS16(Bb + (size_t)(j >> 3) * K + (KT) + (j & 7) * 8, BS + j * 8); \
        }                                                                    \
    }

#define GCOMP(AS, BS)                                                        \
    {                                                                        \
        _Pragma("unroll")                                                    \
        for (int kk = 0; kk < 2; ++kk) {                                     \
            bf16x8 af[4], bfr[4];                                            \
            _Pragma("unroll")                                                \
            for (int m = 0; m < 4; ++m)                                      \
                af[m] = *(const bf16x8*)(AS + (wr + m * 16 + l15) * 64 +     \
                                         kk * 32 + l4 * 8);                  \
            _Pragma("unroll")                                                \
            for (int n = 0; n < 4; ++n)                                      \
                bfr[n] = *(const bf16x8*)(BS + (wc + n * 16 + l15) * 64 +    \
                                          kk * 32 + l4 * 8);                 \
            _Pragma("unroll")                                                \
            for (int m = 0; m < 4; ++m)                                      \
                _Pragma("unroll")                                            \
                for (int n = 0; n < 4; ++n)                                  \
                    acc[m][n] = __builtin_amdgcn_mfma_f32_16x16x32_bf16(     \
                        af[m], bfr[n], acc[m][n], 0, 0, 0);                  \
        }                                                                    \
    }

template <int ACT, int BIASF, int RESF, int OBF, int VSPLIT>
__global__ __launch_bounds__(256) void mfma_gemm(
    const bf16* __restrict__ A, const bf16* __restrict__ Bt,
    const float* __restrict__ bias, const float* __restrict__ res,
    void* __restrict__ outp, bf16* __restrict__ vt, int K, int N) {
    __shared__ bf16 As0[128 * 64];
    __shared__ bf16 Bs0[128 * 64];
    __shared__ bf16 As1[128 * 64];
    __shared__ bf16 Bs1[128 * 64];
    const int tid = threadIdx.x;
    const int lane = tid & 63, wave = tid >> 6;
    const int wr = (wave >> 1) * 64, wc = (wave & 1) * 64;
    const int brow = blockIdx.y * 128, bcol = blockIdx.x * 128;
    const int l15 = lane & 15, l4 = lane >> 4;

    const bf16* Ab = A + (size_t)brow * K;
    const bf16* Bb = Bt + (size_t)bcol * K;

    f32x4 acc[4][4];
#pragma unroll
    for (int m = 0; m < 4; ++m)
#pragma unroll
        for (int n = 0; n < 4; ++n)
            acc[m][n] = (f32x4){0.f, 0.f, 0.f, 0.f};

    GSTAGE(As0, Bs0, 0);   // prologue: stage K-tile 0

    for (int kt = 0; kt < K; kt += 128) {
        __syncthreads();   // drains prefetch of tile kt; guards buffer reuse
        if (kt + 64 < K) GSTAGE(As1, Bs1, kt + 64);
        __builtin_amdgcn_sched_barrier(0);
        GCOMP(As0, Bs0);
        __syncthreads();   // drains prefetch of tile kt+64
        if (kt + 128 < K) GSTAGE(As0, Bs0, kt + 128);
        __builtin_amdgcn_sched_barrier(0);
        if (kt + 64 < K) GCOMP(As1, Bs1);
    }

    // epilogue: C/D layout col=lane&15, row=(lane>>4)*4+reg
    if (VSPLIT && bcol >= 2 * C_) {
        // V third of qkv: write transposed to vt[(b*H+h)*64+d][t] (bf16)
#pragma unroll
        for (int n = 0; n < 4; ++n) {
            const int col = bcol + wc + n * 16 + l15;
            const float bv = BIASF ? bias[col] : 0.f;
            const int hh = (col - 2 * C_) >> 6;
            const int dd = (col - 2 * C_) & 63;
#pragma unroll
            for (int m = 0; m < 4; ++m) {
                const int row0 = brow + wr + m * 16 + l4 * 4;
                const int bq = row0 >> 10, t0 = row0 & (T_ - 1);
                ushort4 pk;
                pk.x = bfb(acc[m][n][0] + bv);
                pk.y = bfb(acc[m][n][1] + bv);
                pk.z = bfb(acc[m][n][2] + bv);
                pk.w = bfb(acc[m][n][3] + bv);
                *(ushort4*)&vt[(((size_t)bq * H_ + hh) * 64 + dd) * T_ + t0] = pk;
            }
        }
        return;
    }
#pragma unroll
    for (int n = 0; n < 4; ++n) {
        const int col = bcol + wc + n * 16 + l15;
        const float bv = BIASF ? bias[col] : 0.f;
#pragma unroll
        for (int m = 0; m < 4; ++m) {
#pragma unroll
            for (int j = 0; j < 4; ++j) {
                const int row = brow + wr + m * 16 + l4 * 4 + j;
                float v = acc[m][n][j] + bv;
                if (ACT == 1) v = 0.5f * v * (1.f + erff(v * 0.70710678118654752440f));
                if (VSPLIT && col < C_) v *= SCL2E;   // pre-scale Q for attn
                if (RESF) v += res[(size_t)row * N + col];
                if (OBF)  ((bf16*)outp)[(size_t)row * N + col] = (bf16)v;
                else      ((float*)outp)[(size_t)row * N + col] = v;
            }
        }
    }
}

// ---------------------------------------------------------------------------
// MFMA flash attention, swapped operands (lane-local softmax). Unchanged r5.
// ---------------------------------------------------------------------------
__device__ __forceinline__ void attn_stage(
    bf16* KN, bf16* VN, int kt,
    const bf16* __restrict__ Kg, const bf16* __restrict__ Vg, int tid) {
    const int r = tid >> 3, bb = tid & 7;
    GLDS16(Kg + (size_t)(kt * 64 + r) * C3_ + ((bb ^ (r & 7)) << 3), KN + tid * 8);
    GLDS16(Vg + (size_t)r * T_ + kt * 64 + ((bb ^ (r & 7)) << 3), VN + tid * 8);
}

__device__ __forceinline__ void attn_step(
    const bf16* KC, const bf16* VC, bf16* KN, bf16* VN,
    const bf16* __restrict__ Kg, const bf16* __restrict__ Vg,
    bf16x8 aq0, bf16x8 aq1, f32x4 (&acc_o)[4], float& mrun, float& lsum,
    int kt, bool pre, bool msk, int qg, int tid, int l15, int g) {
    __syncthreads();                       // prev reads done + own prefetch drained
    if (pre) attn_stage(KN, VN, kt + 1, Kg, Vg, tid);
    __builtin_amdgcn_sched_barrier(0);

    // ---- QK^T (swapped): acc_s[n][j] = S[k = kt*64+n*16+g*4+j][q = qg] ----
    f32x4 acc_s[4];
#pragma unroll
    for (int n = 0; n < 4; ++n) acc_s[n] = (f32x4){0.f, 0.f, 0.f, 0.f};
    __builtin_amdgcn_s_setprio(1);
#pragma unroll
    for (int kk = 0; kk < 2; ++kk) {
        bf16x8 aq = kk ? aq1 : aq0;
        const int cb = kk * 64 + g * 16;
#pragma unroll
        for (int n = 0; n < 4; ++n) {
            const int krow = n * 16 + l15;
            bf16x8 bk = *(const bf16x8*)((const char*)KC + krow * 128 +
                                         (cb ^ ((krow & 7) << 4)));
            acc_s[n] = __builtin_amdgcn_mfma_f32_16x16x32_bf16(
                bk, aq, acc_s[n], 0, 0, 0);
        }
    }
    __builtin_amdgcn_s_setprio(0);

    // ---- lane-local online softmax (q = l15 owned by this lane) ----
    float pv[4][4];
    float rm = -1e30f;
#pragma unroll
    for (int n = 0; n < 4; ++n)
#pragma unroll
        for (int j = 0; j < 4; ++j) {
            float s = acc_s[n][j];
            if (msk && (kt * 64 + n * 16 + g * 4 + j > qg)) s = -1e30f;
            pv[n][j] = s;
            rm = fmaxf(rm, s);
        }
    rm = fmaxf(rm, __shfl_xor(rm, 16));
    rm = fmaxf(rm, __shfl_xor(rm, 32));
    const float mnew = fmaxf(mrun, rm);
    const float fs = exp2f(mrun - mnew);
    mrun = mnew;
    float ps = 0.f;
#pragma unroll
    for (int n = 0; n < 4; ++n)
#pragma unroll
        for (int j = 0; j < 4; ++j) {
            pv[n][j] = exp2f(pv[n][j] - mnew);
            ps += pv[n][j];
        }
    ps += __shfl_xor(ps, 16);
    ps += __shfl_xor(ps, 32);
    lsum = lsum * fs + ps;
#pragma unroll
    for (int n = 0; n < 4; ++n) {
        acc_o[n][0] *= fs; acc_o[n][1] *= fs;
        acc_o[n][2] *= fs; acc_o[n][3] *= fs;
    }

    // ---- pack P to bf16x2 words (in-lane: j-adjacent k) ----
    unsigned int pkw[4][2];
#pragma unroll
    for (int n = 0; n < 4; ++n) {
        pkw[n][0] = ((unsigned int)bfb(pv[n][1]) << 16) | bfb(pv[n][0]);
        pkw[n][1] = ((unsigned int)bfb(pv[n][3]) << 16) | bfb(pv[n][2]);
    }

    // ---- PV (swapped): acc_o[n] += V^T x P^T ; O[d][q=l15] ----
    const int sA = l15 + (((2 * g) & 3) << 4);
    const int sB = l15 + (((2 * g + 1) & 3) << 4);
    __builtin_amdgcn_s_setprio(1);
#pragma unroll
    for (int kk = 0; kk < 2; ++kk) {
        const unsigned int a0 = __shfl((int)pkw[2 * kk + 0][0], sA);
        const unsigned int a1 = __shfl((int)pkw[2 * kk + 0][1], sA);
        const unsigned int a2 = __shfl((int)pkw[2 * kk + 0][0], sB);
        const unsigned int a3 = __shfl((int)pkw[2 * kk + 0][1], sB);
        const unsigned int b0 = __shfl((int)pkw[2 * kk + 1][0], sA);
        const unsigned int b1 = __shfl((int)pkw[2 * kk + 1][1], sA);
        const unsigned int b2 = __shfl((int)pkw[2 * kk + 1][0], sB);
        const unsigned int b3 = __shfl((int)pkw[2 * kk + 1][1], sB);
        u32x4 wd;
        wd[0] = (g & 2) ? b0 : a0;
        wd[1] = (g & 2) ? b1 : a1;
        wd[2] = (g & 2) ? b2 : a2;
        wd[3] = (g & 2) ? b3 : a3;
        bf16x8 ap = __builtin_bit_cast(bf16x8, wd);
        const int cb = kk * 64 + g * 16;
#pragma unroll
        for (int n = 0; n < 4; ++n) {
            const int drow = n * 16 + l15;
            bf16x8 bv = *(const bf16x8*)((const char*)VC + drow * 128 +
                                         (cb ^ ((drow & 7) << 4)));
            acc_o[n] = __builtin_amdgcn_mfma_f32_16x16x32_bf16(
                bv, ap, acc_o[n], 0, 0, 0);
        }
    }
    __builtin_amdgcn_s_setprio(0);
}

__global__ __launch_bounds__(512, 4) void attn_kernel(
    const bf16* __restrict__ qkv, const bf16* __restrict__ vtb,
    bf16* __restrict__ o) {
    __shared__ bf16 Ks0[64 * 64];
    __shared__ bf16 Vt0[64 * 64];
    __shared__ bf16 Ks1[64 * 64];
    __shared__ bf16 Vt1[64 * 64];

    const int qt = 7 - blockIdx.x;          // heavy tiles first
    const int bh = blockIdx.y;
    const int b = bh / H_, h = bh % H_;
    const int tid = threadIdx.x;
    const int w = tid >> 6, lane = tid & 63;
    const int l15 = lane & 15, g = lane >> 4;
    const int qg = qt * 128 + w * 16 + l15; // this lane's q-row (local to bh)

    const bf16* Qg = qkv + ((size_t)(b * T_) + qt * 128) * C3_ + h * 64;
    const bf16* Kg = qkv + (size_t)(b * T_) * C3_ + C_ + h * 64;
    const bf16* Vg = vtb + (size_t)bh * 64 * T_;

    // Q fragments in registers (B-operand: col=l15=q, k=g*8..), pre-scaled
    bf16x8 aq0 = *(const bf16x8*)(Qg + (size_t)(w * 16 + l15) * C3_ + g * 8);
    bf16x8 aq1 = *(const bf16x8*)(Qg + (size_t)(w * 16 + l15) * C3_ + 32 + g * 8);

    attn_stage(Ks0, Vt0, 0, Kg, Vg, tid);   // prologue

    f32x4 acc_o[4];
#pragma unroll
    for (int n = 0; n < 4; ++n) acc_o[n] = (f32x4){0.f, 0.f, 0.f, 0.f};
    float mrun = -1e30f, lsum = 0.f;

    const int ktN = 2 * qt + 1;             // inclusive last k-tile
    const int dmin = 2 * qt + (w >> 2);     // first tile needing mask (per wave)

    for (int kt = 0; kt < ktN; kt += 2) {
        attn_step(Ks0, Vt0, Ks1, Vt1, Kg, Vg, aq0, aq1, acc_o, mrun, lsum,
                  kt, true, kt >= dmin, qg, tid, l15, g);
        attn_step(Ks1, Vt1, Ks0, Vt0, Kg, Vg, aq0, aq1, acc_o, mrun, lsum,
                  kt + 1, kt + 2 <= ktN, kt + 1 >= dmin, qg, tid, l15, g);
    }

    // ---- write O: lane owns q=qg, d = n*16 + g*4 + j ----
    const float inv = 1.f / lsum;
    bf16* op = o + ((size_t)(b * T_) + qg) * C_ + h * 64;
#pragma unroll
    for (int n = 0; n < 4; ++n) {
        ushort4 pk;
        pk.x = bfb(acc_o[n][0] * inv);
        pk.y = bfb(acc_o[n][1] * inv);
        pk.z = bfb(acc_o[n][2] * inv);
        pk.w = bfb(acc_o[n][3] * inv);
        *(ushort4*)&op[n * 16 + g * 4] = pk;
    }
}

// ---------------------------------------------------------------------------
// Launch
// ---------------------------------------------------------------------------
extern "C" void kernel_launch(void* const* d_in, const int* in_sizes, int n_in,
                              void* d_out, int out_size, void* d_ws, size_t ws_size,
                              hipStream_t stream) {
    (void)in_sizes; (void)n_in; (void)out_size; (void)ws_size;
    const int*   idx  = (const int*)d_in[0];
    const int*   y    = (const int*)d_in[1];
    const float* tok  = (const float*)d_in[2];
    const float* pos  = (const float*)d_in[3];
    const float* cls  = (const float*)d_in[4];
    const float* ln1w = (const float*)d_in[5];
    const float* ln1b = (const float*)d_in[6];
    const float* aw   = (const float*)d_in[7];
    const float* ab   = (const float*)d_in[8];
    const float* pw   = (const float*)d_in[9];
    const float* pb   = (const float*)d_in[10];
    const float* ln2w = (const float*)d_in[11];
    const float* ln2b = (const float*)d_in[12];
    const float* w1   = (const float*)d_in[13];
    const float* b1   = (const float*)d_in[14];
    const float* w2   = (const float*)d_in[15];
    const float* b2   = (const float*)d_in[16];
    const float* lnfw = (const float*)d_in[17];
    const float* lnfb = (const float*)d_in[18];
    const float* hw   = (const float*)d_in[19];
    float* out = (float*)d_out;

    // Workspace: x(f32) | union{qkv bf16 + vt bf16 | mid bf16} | hbf | weights
    char* wsp = (char*)d_ws;
    float* x   = (float*)wsp;  wsp += (size_t)M_ * C_ * 4;
    char*  uni = wsp;          wsp += (size_t)M_ * C4_ * 2;
    bf16*  qkv = (bf16*)uni;                                   // M x 3C
    bf16*  vtb = (bf16*)(uni + (size_t)M_ * C3_ * 2);          // B*H*64 x T
    bf16*  mid = (bf16*)uni;                                   // M x 4C
    bf16*  hbf = (bf16*)wsp;   wsp += (size_t)M_ * C_ * 2;
    bf16*  awt = (bf16*)wsp;   wsp += (size_t)L_ * C_ * C3_ * 2;
    bf16*  pwt = (bf16*)wsp;   wsp += (size_t)L_ * C_ * C_  * 2;
    bf16*  w1t = (bf16*)wsp;   wsp += (size_t)L_ * C_ * C4_ * 2;
    bf16*  w2t = (bf16*)wsp;   wsp += (size_t)L_ * C4_ * C_ * 2;
    bf16*  hwt = (bf16*)wsp;   wsp += (size_t)C_ * V_ * 2;

    wt_kernel<<<dim3(C3_ / 32, C_ / 32, L_), 256, 0, stream>>>(aw, awt, C_, C3_);
    wt_kernel<<<dim3(C_ / 32, C_ / 32, L_), 256, 0, stream>>>(pw, pwt, C_, C_);
    wt_kernel<<<dim3(C4_ / 32, C_ / 32, L_), 256, 0, stream>>>(w1, w1t, C_, C4_);
    wt_kernel<<<dim3(C_ / 32, C4_ / 32, L_), 256, 0, stream>>>(w2, w2t, C4_, C_);
    wt_kernel<<<dim3(V_ / 32, C_ / 32, 1), 256, 0, stream>>>(hw, hwt, C_, V_);

    embed_kernel<<<M_, 256, 0, stream>>>(idx, y, tok, pos, cls, x);

    for (int l = 0; l < L_; ++l) {
        ln_kernel<<<M_ / 4, 256, 0, stream>>>(x, ln1w + l * C_, ln1b + l * C_, hbf);

        mfma_gemm<0, 1, 0, 1, 1><<<dim3(C3_ / 128, M_ / 128), 256, 0, stream>>>(
            hbf, awt + (size_t)l * C_ * C3_, ab + (size_t)l * C3_, nullptr,
            qkv, vtb, C_, C3_);

        attn_kernel<<<dim3(T_ / 128, B_ * H_), 512, 0, stream>>>(qkv, vtb, hbf);

        mfma_gemm<0, 1, 1, 0, 0><<<dim3(C_ / 128, M_ / 128), 256, 0, stream>>>(
            hbf, pwt + (size_t)l * C_ * C_, pb + (size_t)l * C_, x,
            x, nullptr, C_, C_);

        ln_kernel<<<M_ / 4, 256, 0, stream>>>(x, ln2w + l * C_, ln2b + l * C_, hbf);

        mfma_gemm<1, 1, 0, 1, 0><<<dim3(C4_ / 128, M_ / 128), 256, 0, stream>>>(
            hbf, w1t + (size_t)l * C_ * C4_, b1 + (size_t)l * C4_, nullptr,
            mid, nullptr, C_, C4_);

        mfma_gemm<0, 1, 1, 0, 0><<<dim3(C_ / 128, M_ / 128), 256, 0, stream>>>(
            mid, w2t + (size_t)l * C4_ * C_, b2 + (size_t)l * C_, x,
            x, nullptr, C4_, C_);
    }

    ln_kernel<<<M_ / 4, 256, 0, stream>>>(x, lnfw, lnfb, hbf);

    mfma_gemm<0, 0, 0, 0, 0><<<dim3(V_ / 128, M_ / 128), 256, 0, stream>>>(
        hbf, hwt, nullptr, nullptr, out, nullptr, C_, V_);
}